// Round 13
// baseline (290.807 us; speedup 1.0000x reference)
//
#include <hip/hip_runtime.h>
#include <hip/hip_bf16.h>

using bf16x8 = __attribute__((ext_vector_type(8))) short;
using f32x4  = __attribute__((ext_vector_type(4))) float;

#define DEVI __device__ __forceinline__

DEVI unsigned short bf16r(float f)
{
    return __builtin_bit_cast(unsigned short, __float2bfloat16(f));
}

DEVI bf16x8 cvt8(const f32x4 a, const f32x4 b)
{
    bf16x8 r;
#pragma unroll
    for (int j = 0; j < 4; ++j) {
        r[j]     = (short)bf16r(a[j]);
        r[4 + j] = (short)bf16r(b[j]);
    }
    return r;
}

// ---------------- gather: x[b][:] = bf16(E[inp[b]][:]) ----------------
__global__ __launch_bounds__(256) void k_gather(const float* __restrict__ E,
                                                const int* __restrict__ inp,
                                                unsigned short* __restrict__ x)
{
    const int b = blockIdx.x;
    const long r = inp[b];
    const f32x4 v = ((const f32x4*)(E + r * 1024L))[threadIdx.x];
    ushort4 o;
    o.x = bf16r(v[0]); o.y = bf16r(v[1]); o.z = bf16r(v[2]); o.w = bf16r(v[3]);
    ((ushort4*)(x + (long)b * 1024L))[threadIdx.x] = o;
}

// ---------------- fp32 -> bf16 bulk convert ----------------
__global__ __launch_bounds__(256) void k_cvtn(const float* __restrict__ in,
                                              unsigned short* __restrict__ out)
{
    const long i = (blockIdx.x * 256L + threadIdx.x) * 8;
    const f32x4 a = *(const f32x4*)(in + i);
    const f32x4 b = *(const f32x4*)(in + i + 4);
    *(bf16x8*)(out + i) = cvt8(a, b);
}

// =====================================================================
// GEMM core: BM=512 (= full M, A read ONCE per block, B read ONCE total),
// BN=128, BK=32, 512 threads = 8 waves (4M x 2N; per-wave 128x64 out,
// acc[8][4], 32 MFMA/K-tile). VMEM per K-tile: A 32KB bf16 + B 16KB fp32
// = 48KB for 512x128x32 FLOPs -> ~half the bytes/FLOP of the 128^2 tiles.
//   A: bf16 -> 4 bf16x8 reg loads/thread -> swizzled ds_write
//   B: fp32 -> 2 f32x4 reg loads/thread  -> cvt8 -> swizzled ds_write
// Double-buffered (2 x 40KB = 80KB LDS); R11's verified leapfrog pipeline:
// s_waitcnt vmcnt(6) keeps the next K-tile's 6 loads in flight across the
// single per-K-tile barrier. LDS rows = 32 elems = 64B, slot = j^(row&3)
// on write and read (max 2-way bank alias = free).
// =====================================================================

DEVI void mfma_tile512(const char* sA, const char* sB, int l, int wr, int wc,
                       f32x4 (&acc)[8][4])
{
    const int j = l >> 4;
    bf16x8 af[8], bq[4];
#pragma unroll
    for (int m = 0; m < 8; ++m) {
        const int row = wr * 128 + m * 16 + (l & 15);
        af[m] = *(const bf16x8*)(sA + row * 64 + ((j ^ (row & 3)) << 4));
    }
#pragma unroll
    for (int n = 0; n < 4; ++n) {
        const int row = wc * 64 + n * 16 + (l & 15);
        bq[n] = *(const bf16x8*)(sB + row * 64 + ((j ^ (row & 3)) << 4));
    }
#pragma unroll
    for (int m = 0; m < 8; ++m)
#pragma unroll
        for (int n = 0; n < 4; ++n)
            acc[m][n] = __builtin_amdgcn_mfma_f32_16x16x32_bf16(
                af[m], bq[n], acc[m][n], 0, 0, 0);
}

template <bool CLAMP>
DEVI void gemm_core512(const unsigned short* __restrict__ A, long lda,
                       const float* __restrict__ B, long ldb, long bcol0,
                       long bmax, int nt, long kbase, int t, char* lds,
                       f32x4 (&acc)[8][4])
{
    char* sA0 = lds;                 // 32KB
    char* sA1 = lds + 32768;
    char* sB0 = lds + 65536;         // 8KB
    char* sB1 = lds + 73728;
    const int l = t & 63, w = t >> 6, wr = w >> 1, wc = w & 1;

    // A: 512 rows x 4 granules (16B = 8 bf16) = 2048 -> 4/thread.
    const unsigned short* ap[4];
    int aswz[4];
#pragma unroll
    for (int i = 0; i < 4; ++i) {
        const int g = i * 512 + t, row = g >> 2, j = g & 3;
        ap[i] = A + row * lda + kbase + j * 8;
        aswz[i] = row * 64 + ((j ^ (row & 3)) << 4);
    }
    // B: 128 rows x 4 segments (8 fp32 = 32B) = 512 -> 1/thread.
    const int brow = t >> 2, bseg = t & 3;
    long br = bcol0 + brow;
    if (CLAMP) br = (br < bmax) ? br : (bmax - 1);
    const float* bp = B + br * ldb + kbase + bseg * 8;
    const int bswz = brow * 64 + ((bseg ^ (brow & 3)) << 4);

    bf16x8 ra0[4], ra1[4];
    f32x4 rb0[2], rb1[2];

#define LOADR(as, bs)                                                          \
    do {                                                                       \
        _Pragma("unroll") for (int i = 0; i < 4; ++i) {                        \
            as[i] = *(const bf16x8*)ap[i];                                     \
            ap[i] += 32;                                                       \
        }                                                                      \
        bs[0] = *(const f32x4*)bp;                                             \
        bs[1] = *(const f32x4*)(bp + 4);                                       \
        bp += 32;                                                              \
    } while (0)
#define WRLDS(sa, sb, as, bs)                                                  \
    do {                                                                       \
        _Pragma("unroll") for (int i = 0; i < 4; ++i)                          \
            *(bf16x8*)((sa) + aswz[i]) = as[i];                                \
        *(bf16x8*)((sb) + bswz) = cvt8(bs[0], bs[1]);                          \
    } while (0)
#define WAITV6  asm volatile("s_waitcnt vmcnt(6)" ::: "memory")
#define WAITV0  asm volatile("s_waitcnt vmcnt(0)" ::: "memory")
#define WAITL0  asm volatile("s_waitcnt lgkmcnt(0)" ::: "memory")
#define BARRIER __builtin_amdgcn_s_barrier()

    // Prologue: K-tiles 0,1 in regs; write 0; issue 2.
    LOADR(ra0, rb0);                 // set0 <- kt 0
    LOADR(ra1, rb1);                 // set1 <- kt 1
    WAITV6;                          // set0 ready (set1 in flight)
    WRLDS(sA0, sB0, ra0, rb0);
    LOADR(ra0, rb0);                 // set0 <- kt 2 (in flight)
    WAITL0; BARRIER;                 // buf0 visible

    for (int kt = 0; kt < nt; kt += 2) {
        // EVEN: write kt+1 -> buf1 (from set1), compute kt (buf0).
        if (kt + 2 < nt) WAITV6; else WAITV0;       // set1 (kt+1) ready
        WRLDS(sA1, sB1, ra1, rb1);
        if (kt + 3 < nt) LOADR(ra1, rb1);           // set1 <- kt+3
        mfma_tile512(sA0, sB0, l, wr, wc, acc);
        WAITL0; BARRIER;                            // buf1 visible; buf0 free
        // ODD: write kt+2 -> buf0 (from set0), compute kt+1 (buf1).
        if (kt + 2 < nt) {
            if (kt + 3 < nt) WAITV6; else WAITV0;   // set0 (kt+2) ready
            WRLDS(sA0, sB0, ra0, rb0);
            if (kt + 4 < nt) LOADR(ra0, rb0);       // set0 <- kt+4
        }
        mfma_tile512(sA1, sB1, l, wr, wc, acc);
        WAITL0; BARRIER;
    }
#undef LOADR
#undef WRLDS
#undef WAITV6
#undef WAITV0
#undef WAITL0
#undef BARRIER
}

// ---------------- gates GEMM: 192 blocks = 3 z-chunks x 64 ntiles ----------
// z=0: x@Wx^T (K=1024); z=1: h0@Wh^T[,0:1024); z=2: h0@Wh^T[,1024:2048).
__global__ __launch_bounds__(512) void k_gates(
    const unsigned short* __restrict__ xb, const float* __restrict__ Wx,
    const unsigned short* __restrict__ h0b, const float* __restrict__ Wh,
    float* __restrict__ g0, float* __restrict__ g1, float* __restrict__ g2)
{
    extern __shared__ __align__(16) char lds[];
    const int t = threadIdx.x;
    const int bid = blockIdx.x;
    const int z = bid >> 6;
    const int ntile = bid & 63;

    const unsigned short* A; const float* B; long lda, ldb, kbase; float* C;
    if (z == 0)      { A = xb;  lda = 1024; B = Wx; ldb = 1024; kbase = 0;    C = g0; }
    else if (z == 1) { A = h0b; lda = 2048; B = Wh; ldb = 2048; kbase = 0;    C = g1; }
    else             { A = h0b; lda = 2048; B = Wh; ldb = 2048; kbase = 1024; C = g2; }

    f32x4 acc[8][4] = {};
    gemm_core512<false>(A, lda, B, ldb, (long)ntile * 128, 1L << 40, 32, kbase,
                        t, lds, acc);

    const int l = t & 63, w = t >> 6, wr = w >> 1, wc = w & 1;
    const int lc = l & 15, r4 = (l >> 4) * 4;
#pragma unroll
    for (int n = 0; n < 4; ++n) {
        const long col = (long)ntile * 128 + wc * 64 + n * 16 + lc;
#pragma unroll
        for (int m = 0; m < 8; ++m) {
            const long row = wr * 128 + m * 16 + r4;
#pragma unroll
            for (int r = 0; r < 4; ++r)
                C[(row + r) * 8192 + col] = acc[m][n][r];
        }
    }
}

// ---------------- decoder GEMM: out = hx @ Wd^T + bd (fp32 Wd, read once) ----
// 393 blocks, BM=512 (full M): every Wd byte consumed by exactly one block.
__global__ __launch_bounds__(512) void k_dec(
    const unsigned short* __restrict__ hxb, const float* __restrict__ Wd,
    const float* __restrict__ bd, float* __restrict__ out)
{
    extern __shared__ __align__(16) char lds[];
    const int t = threadIdx.x;
    const int ntile = blockIdx.x;              // 0..392
    const long N = 50257;

    f32x4 acc[8][4] = {};
    gemm_core512<true>(hxb, 2048, Wd, 2048, (long)ntile * 128, N, 64, 0,
                       t, lds, acc);

    const int l = t & 63, w = t >> 6, wr = w >> 1, wc = w & 1;
    const int lc = l & 15, r4 = (l >> 4) * 4;
#pragma unroll
    for (int n = 0; n < 4; ++n) {
        const long col = (long)ntile * 128 + wc * 64 + n * 16 + lc;
        if (col >= N) continue;
        const float bias = bd[col];
#pragma unroll
        for (int m = 0; m < 8; ++m) {
            const long row = wr * 128 + m * 16 + r4;
#pragma unroll
            for (int r = 0; r < 4; ++r)
                out[(row + r) * N + col] = acc[m][n][r] + bias;
        }
    }
}

// ---------------- elementwise LSTM cell: combine 3 partials + biases ----------------
__global__ __launch_bounds__(256) void k_lstm(
    const float* __restrict__ g0, const float* __restrict__ g1,
    const float* __restrict__ g2, const float* __restrict__ bx,
    const float* __restrict__ bh, const float* __restrict__ c0,
    float* __restrict__ hx, float* __restrict__ cx,
    unsigned short* __restrict__ hxb)
{
    const int i = blockIdx.x * 256 + threadIdx.x;
    const int b = i >> 9;
    const int hc = (i & 511) << 2;
    const long base = (long)b * 8192;

    f32x4 g[4];
#pragma unroll
    for (int gi = 0; gi < 4; ++gi) {
        const long off = base + gi * 2048 + hc;
        const int boff = gi * 2048 + hc;
        g[gi] = *(const f32x4*)(g0 + off);
        g[gi] += *(const f32x4*)(g1 + off);
        g[gi] += *(const f32x4*)(g2 + off);
        g[gi] += *(const f32x4*)(bx + boff);
        g[gi] += *(const f32x4*)(bh + boff);
    }
    const f32x4 c0v = *(const f32x4*)(c0 + (long)b * 2048 + hc);

    f32x4 cv, hv;
    ushort4 hb;
#pragma unroll
    for (int j = 0; j < 4; ++j) {
        const float fg = 1.f / (1.f + __expf(-g[0][j]));
        const float ig = 1.f / (1.f + __expf(-g[1][j]));
        const float og = 1.f / (1.f + __expf(-g[2][j]));
        const float e2 = __expf(2.f * g[3][j]);
        const float ct = 1.f - 2.f / (e2 + 1.f);
        const float c  = fg * c0v[j] + ig * ct;
        const float e2c = __expf(2.f * c);
        const float th  = 1.f - 2.f / (e2c + 1.f);
        cv[j] = c;
        hv[j] = og * th;
    }
    hb.x = bf16r(hv[0]); hb.y = bf16r(hv[1]); hb.z = bf16r(hv[2]); hb.w = bf16r(hv[3]);

    const long o = (long)b * 2048 + hc;
    *(f32x4*)(cx + o) = cv;
    *(f32x4*)(hx + o) = hv;
    *(ushort4*)(hxb + o) = hb;
}

// ---------------- launch ----------------
extern "C" void kernel_launch(void* const* d_in, const int* in_sizes, int n_in,
                              void* d_out, int out_size, void* d_ws, size_t ws_size,
                              hipStream_t stream)
{
    const int*   inp = (const int*)d_in[0];
    const float* h0  = (const float*)d_in[1];
    const float* c0  = (const float*)d_in[2];
    const float* E   = (const float*)d_in[3];
    const float* Wx  = (const float*)d_in[4];   // (8192,1024)
    const float* bx  = (const float*)d_in[5];
    const float* Wh  = (const float*)d_in[6];   // (8192,2048)
    const float* bh  = (const float*)d_in[7];
    const float* Wd  = (const float*)d_in[8];   // (50257,2048)
    const float* bd  = (const float*)d_in[9];

    float* out = (float*)d_out;                 // [512][50257]
    float* hx  = out + 512L * 50257L;           // [512][2048]
    float* cx  = hx + 512L * 2048L;

    // Scratch in the out region (all consumed before k_dec overwrites out):
    //   xb @ 0 (0.5MB), g0 @ 1M floats, g1 @ 5M, g2 @ 9M, h0b @ 13M floats.
    unsigned short* xb  = (unsigned short*)out;
    float* g0 = out + (1L << 20);
    float* g1 = out + (5L << 20);
    float* g2 = out + (9L << 20);
    unsigned short* h0b = (unsigned short*)(out + (13L << 20));
    // hxb read during k_dec (which writes out) -> lives in d_ws.
    unsigned short* hxb = (unsigned short*)d_ws;

    k_gather<<<512, 256, 0, stream>>>(E, inp, xb);
    k_cvtn<<<512, 256, 0, stream>>>(h0, h0b);

    k_gates<<<192, 512, 81920, stream>>>(xb, Wx, h0b, Wh, g0, g1, g2);

    k_lstm<<<1024, 256, 0, stream>>>(g0, g1, g2, bx, bh, c0, hx, cx, hxb);

    k_dec<<<393, 512, 81920, stream>>>(hxb, Wd, bd, out);
}